// Round 1
// 242.959 us; speedup vs baseline: 1.1279x; 1.1279x over previous
//
#include <hip/hip_runtime.h>
#include <hip/hip_bf16.h>

#define T_LEN 1024
#define NH    16
#define CH    64
#define LSTR  72        // LDS bf16 row stride in shorts: 144 B, 16B-aligned
#define OSTR  68        // epilogue fp32 row stride in floats

typedef __attribute__((ext_vector_type(8))) short short8;
typedef __attribute__((ext_vector_type(4))) float floatx4;
typedef unsigned long long u64;

__device__ __forceinline__ short f2bf(float x) {
    __hip_bfloat16 b = __float2bfloat16(x);   // RNE
    return *(short*)&b;
}
// col-block XOR swizzle: breaks the row-stride-16 (==0 mod 32 banks) conflicts
// of transposed b16 staging writes while keeping 8-short frag reads contiguous.
__device__ __forceinline__ int swz(int row) { return ((row >> 3) & 7) << 3; }

// ---- mask bit-pack: (8,1024,1024) int32 -> (8,1024,16) u64 via wave ballot ----
__global__ __launch_bounds__(256)
void pack_mask_kernel(const int* __restrict__ mask, u64* __restrict__ pm)
{
    const int NW = 8 * T_LEN * (T_LEN / 64);   // 131072 words
    const int lane = threadIdx.x & 63;
    const int gw = (int)((blockIdx.x * blockDim.x + threadIdx.x) >> 6);
    const int nw = (int)((gridDim.x * blockDim.x) >> 6);
    for (int w0 = gw; w0 < NW; w0 += 4 * nw) {
        int v[4];
        #pragma unroll
        for (int i = 0; i < 4; ++i) {
            const int w = w0 + i * nw;
            v[i] = (w < NW) ? mask[(size_t)w * 64 + lane] : 0;
        }
        #pragma unroll
        for (int i = 0; i < 4; ++i) {
            const int w = w0 + i * nw;
            const u64 bb = __ballot(v[i] != 0);   // bit i = lane i = col within word
            if (lane == 0 && w < NW) pm[w] = bb;
        }
    }
}

// One block = 8 waves = 512 threads: one (head-batch, 128-row Q tile).
// Double-buffered K/V LDS (1 barrier/iter), reg-prefetched global loads,
// XOR-swizzled transposed staging, packed-bit mask, no-max softmax with
// ones-MFMA row sums.
template<bool PM>
__global__ __launch_bounds__(512, 4)
void qkv_attn_kernel(const float* __restrict__ qkv,
                     const int* __restrict__ mask,
                     const u64* __restrict__ pm,
                     const float* __restrict__ qk_bias,
                     float* __restrict__ out)
{
    // rows of LSTR shorts: Q[128] | K0|V0|K1|V1 [64 each] | P[8 waves x 16]
    __shared__ __align__(16) char smem[(128 + 4 * 64 + 128) * LSTR * 2];  // 73728 B
    short* Qs  = (short*)smem;            // [t][c]   swizzled
    short* Ks0 = Qs  + 128 * LSTR;        // [s][c]   swizzled
    short* Vs0 = Ks0 + 64 * LSTR;         // [c][s]   linear
    short* Ks1 = Vs0 + 64 * LSTR;
    short* Vs1 = Ks1 + 64 * LSTR;
    short* Ps  = Vs1 + 64 * LSTR;         // per-wave [16][s] swizzled
    float* Os  = (float*)smem;            // epilogue reuse: 128 x OSTR fp32 = 34816 B

    const int tid  = threadIdx.x;
    const int wave = tid >> 6;
    const int lane = tid & 63;
    const int quad = lane >> 4;
    const int l16  = lane & 15;

    const int bh    = blockIdx.x;   // 0..127: consecutive bh -> XCD round-robin;
    const int qtile = blockIdx.y;   // 0..7:   stride-128 ids keep a bh on ONE XCD
    const int b     = bh >> 4;
    const int h     = bh & 15;
    const int t0    = qtile * 128;

    const size_t qbase = ((size_t)b * (3 * NH * CH) + (size_t)h * (3 * CH)) * T_LEN;
    const float* kp = qkv + qbase + (size_t)CH * T_LEN;
    const float* vp = qkv + qbase + (size_t)(2 * CH) * T_LEN;

    const float bias = qk_bias[0];

    const int c64 = tid >> 3;          // 0..63 channel row
    const int sse = (tid & 7) * 8;     // K/V staging: 8 s per thread
    const int tse = (tid & 7) * 16;    // Q staging:   16 t per thread

    const float* kpr = kp + (size_t)c64 * T_LEN;
    const float* vpr = vp + (size_t)c64 * T_LEN;

    const int trow = t0 + wave * 16 + quad * 4;
    const u64* pmb = PM ? pm + ((size_t)(h & 7) * T_LEN + trow) * (T_LEN / 64) : nullptr;
    const int* mbase = mask + (size_t)(h & 7) * T_LEN * T_LEN;

    // ---- issue prefetch of K/V tile 0 + mask words 0 ----
    float4 kf0 = *(const float4*)(kpr + sse);
    float4 kf1 = *(const float4*)(kpr + sse + 4);
    float4 vf0 = *(const float4*)(vpr + sse);
    float4 vf1 = *(const float4*)(vpr + sse + 4);
    u64 mnxt[4];
    if (PM) {
        #pragma unroll
        for (int r = 0; r < 4; ++r) mnxt[r] = pmb[r * (T_LEN / 64)];
    }

    // ---- stage Q transposed + swizzled (fp32 -> bf16) ----
    {
        const float* src = qkv + qbase + (size_t)c64 * T_LEN + t0 + tse;
        #pragma unroll
        for (int k = 0; k < 4; ++k) {
            float4 f = *(const float4*)(src + 4 * k);
            const int t  = tse + 4 * k;
            const int cs = c64 ^ swz(t);           // t..t+3 share (t>>3)
            Qs[(t + 0) * LSTR + cs] = f2bf(f.x);
            Qs[(t + 1) * LSTR + cs] = f2bf(f.y);
            Qs[(t + 2) * LSTR + cs] = f2bf(f.z);
            Qs[(t + 3) * LSTR + cs] = f2bf(f.w);
        }
    }

    // ---- stage K/V tile 0 into buf0 ----
    const int ksw = c64 ^ swz(sse);                // sse..sse+7 share (s>>3)
    {
        short kb[8] = { f2bf(kf0.x), f2bf(kf0.y), f2bf(kf0.z), f2bf(kf0.w),
                        f2bf(kf1.x), f2bf(kf1.y), f2bf(kf1.z), f2bf(kf1.w) };
        #pragma unroll
        for (int j = 0; j < 8; ++j) Ks0[(sse + j) * LSTR + ksw] = kb[j];
        short8 vb = { f2bf(vf0.x), f2bf(vf0.y), f2bf(vf0.z), f2bf(vf0.w),
                      f2bf(vf1.x), f2bf(vf1.y), f2bf(vf1.z), f2bf(vf1.w) };
        *(short8*)&Vs0[c64 * LSTR + sse] = vb;
    }
    __syncthreads();

    // ---- loop-invariant Q fragments ----
    const int qrow = wave * 16 + l16;
    const short8 aq0 = *(const short8*)&Qs[qrow * LSTR + ((quad * 8) ^ swz(qrow))];
    const short8 aq1 = *(const short8*)&Qs[qrow * LSTR + ((quad * 8 + 32) ^ swz(qrow))];

    const short one_bf = (short)0x3F80;
    const short8 ones8 = (short8){one_bf, one_bf, one_bf, one_bf,
                                  one_bf, one_bf, one_bf, one_bf};

    floatx4 o[4], ol;
    #pragma unroll
    for (int i = 0; i < 4; ++i) o[i] = (floatx4){0.f, 0.f, 0.f, 0.f};
    ol = (floatx4){0.f, 0.f, 0.f, 0.f};

    short* Pw = Ps + wave * 16 * LSTR;
    const int psw   = (quad >> 1) << 3;                    // == ((quad*4+r)>>3)<<3
    const int apof0 = (quad * 8)      ^ ((l16 >> 3) << 3);
    const int apof1 = (quad * 8 + 32) ^ ((l16 >> 3) << 3);

    for (int it = 0; it < 16; ++it) {
        const int s0 = it * 64;
        const short* Kc = (it & 1) ? Ks1 : Ks0;
        const short* Vc = (it & 1) ? Vs1 : Vs0;
        short* Kd = (it & 1) ? Ks0 : Ks1;
        short* Vd = (it & 1) ? Vs0 : Vs1;

        // roll mask regs; issue next-tile global loads (hidden under compute)
        u64 mcur[4];
        int mreg[4][4];
        if (PM) {
            #pragma unroll
            for (int r = 0; r < 4; ++r) mcur[r] = mnxt[r];
        } else {
            #pragma unroll
            for (int sub = 0; sub < 4; ++sub)
                #pragma unroll
                for (int r = 0; r < 4; ++r)
                    mreg[sub][r] = mbase[(size_t)(trow + r) * T_LEN + s0 + sub * 16 + l16];
        }
        if (it < 15) {
            kf0 = *(const float4*)(kpr + s0 + 64 + sse);
            kf1 = *(const float4*)(kpr + s0 + 64 + sse + 4);
            vf0 = *(const float4*)(vpr + s0 + 64 + sse);
            vf1 = *(const float4*)(vpr + s0 + 64 + sse + 4);
            if (PM) {
                #pragma unroll
                for (int r = 0; r < 4; ++r) mnxt[r] = pmb[r * (T_LEN / 64) + (it + 1)];
            }
        }

        unsigned mlo[4], mhi[4];
        if (PM) {
            #pragma unroll
            for (int r = 0; r < 4; ++r) {
                const u64 sr = mcur[r] >> l16;
                mlo[r] = (unsigned)sr;
                mhi[r] = (unsigned)(sr >> 32);
            }
        }

        // ---- S = (QK^T)*0.125 + bias -> P = exp(S) masked, no max ----
        #pragma unroll
        for (int sub = 0; sub < 4; ++sub) {
            const int srow = sub * 16 + l16;
            const int ss   = swz(srow);
            const short8 bk0 = *(const short8*)&Kc[srow * LSTR + ((quad * 8) ^ ss)];
            const short8 bk1 = *(const short8*)&Kc[srow * LSTR + ((quad * 8 + 32) ^ ss)];
            floatx4 acc = (floatx4){0.f, 0.f, 0.f, 0.f};
            acc = __builtin_amdgcn_mfma_f32_16x16x32_bf16(aq0, bk0, acc, 0, 0, 0);
            acc = __builtin_amdgcn_mfma_f32_16x16x32_bf16(aq1, bk1, acc, 0, 0, 0);
            const unsigned bsel = (sub & 1) ? 0x10000u : 1u;
            #pragma unroll
            for (int r = 0; r < 4; ++r) {
                bool keep;
                if (PM) keep = (((sub & 2) ? mhi[r] : mlo[r]) & bsel) != 0;
                else    keep = (mreg[sub][r] != 0);
                const float e = __expf(fmaf(acc[r], 0.125f, bias));
                Pw[(quad * 4 + r) * LSTR + ((sub * 16 + l16) ^ psw)] = f2bf(keep ? e : 0.f);
            }
        }

        // ---- per-wave P fragments (no barrier needed: wave-private) ----
        const short8 ap0 = *(const short8*)&Pw[l16 * LSTR + apof0];
        const short8 ap1 = *(const short8*)&Pw[l16 * LSTR + apof1];

        // ---- O += P V ; l += P . 1 ----
        __builtin_amdgcn_s_setprio(1);
        #pragma unroll
        for (int csub = 0; csub < 4; ++csub) {
            const int vrow = csub * 16 + l16;
            const short8 bv0 = *(const short8*)&Vc[vrow * LSTR + quad * 8];
            const short8 bv1 = *(const short8*)&Vc[vrow * LSTR + quad * 8 + 32];
            o[csub] = __builtin_amdgcn_mfma_f32_16x16x32_bf16(ap0, bv0, o[csub], 0, 0, 0);
            o[csub] = __builtin_amdgcn_mfma_f32_16x16x32_bf16(ap1, bv1, o[csub], 0, 0, 0);
        }
        ol = __builtin_amdgcn_mfma_f32_16x16x32_bf16(ap0, ones8, ol, 0, 0, 0);
        ol = __builtin_amdgcn_mfma_f32_16x16x32_bf16(ap1, ones8, ol, 0, 0, 0);
        __builtin_amdgcn_s_setprio(0);

        // ---- write prefetched next tile into the other buffer; single barrier ----
        if (it < 15) {
            short kb[8] = { f2bf(kf0.x), f2bf(kf0.y), f2bf(kf0.z), f2bf(kf0.w),
                            f2bf(kf1.x), f2bf(kf1.y), f2bf(kf1.z), f2bf(kf1.w) };
            #pragma unroll
            for (int j = 0; j < 8; ++j) Kd[(sse + j) * LSTR + ksw] = kb[j];
            short8 vb = { f2bf(vf0.x), f2bf(vf0.y), f2bf(vf0.z), f2bf(vf0.w),
                          f2bf(vf1.x), f2bf(vf1.y), f2bf(vf1.z), f2bf(vf1.w) };
            *(short8*)&Vd[c64 * LSTR + sse] = vb;
            __syncthreads();
        }
    }

    // ---- epilogue: normalize, restage fp32 via LDS for coalesced [c][t] stores ----
    __syncthreads();   // all waves done computing before Os overwrites Qs/buf0
    float inv[4];
    #pragma unroll
    for (int r = 0; r < 4; ++r) inv[r] = (ol[r] > 0.f) ? 1.f / ol[r] : 0.f;
    const int osw = wave << 3;                     // == ((t>>4)<<3), t>>4 = wave
    #pragma unroll
    for (int csub = 0; csub < 4; ++csub)
        #pragma unroll
        for (int r = 0; r < 4; ++r)
            Os[(wave * 16 + quad * 4 + r) * OSTR + ((csub * 16 + l16) ^ osw)] =
                o[csub][r] * inv[r];
    __syncthreads();
    {
        const int g  = (tid & 7) << 3;             // == ((t>>4)<<3), t>>4 = tid&7
        const int cg = c64 ^ g;
        float* dst = out + ((size_t)b * (NH * CH) + (size_t)h * CH + c64) * T_LEN + t0 + tse;
        #pragma unroll
        for (int k = 0; k < 4; ++k) {
            const int t = tse + 4 * k;
            float4 f;
            f.x = Os[(t + 0) * OSTR + cg];
            f.y = Os[(t + 1) * OSTR + cg];
            f.z = Os[(t + 2) * OSTR + cg];
            f.w = Os[(t + 3) * OSTR + cg];
            *(float4*)(dst + 4 * k) = f;
        }
    }
}

extern "C" void kernel_launch(void* const* d_in, const int* in_sizes, int n_in,
                              void* d_out, int out_size, void* d_ws, size_t ws_size,
                              hipStream_t stream) {
    const float* qkv     = (const float*)d_in[0];
    const int*   mask    = (const int*)d_in[1];
    const float* qk_bias = (const float*)d_in[2];
    float*       out     = (float*)d_out;

    const size_t pm_bytes = (size_t)8 * T_LEN * (T_LEN / 64) * sizeof(u64);  // 1 MiB
    u64* pm = nullptr;
    if (d_ws && ws_size >= pm_bytes) {
        pm = (u64*)d_ws;
        pack_mask_kernel<<<2048, 256, 0, stream>>>(mask, pm);
    }

    dim3 grid(8 * NH, T_LEN / 128);  // (head-batches, q-tiles) = (128, 8)
    if (pm) qkv_attn_kernel<true ><<<grid, 512, 0, stream>>>(qkv, mask, pm, qk_bias, out);
    else    qkv_attn_kernel<false><<<grid, 512, 0, stream>>>(qkv, mask, nullptr, qk_bias, out);
}